// Round 10
// baseline (1634.603 us; speedup 1.0000x reference)
//
#include <hip/hip_runtime.h>
#include <hip/hip_bf16.h>

#define BQ 8192
typedef __attribute__((ext_vector_type(8))) __bf16 bf16x8;
typedef __attribute__((ext_vector_type(4))) float f32x4;
typedef __attribute__((ext_vector_type(4))) int int4v;

__device__ __forceinline__ f32x4 mfma16(bf16x8 a, bf16x8 b, f32x4 c) {
    return __builtin_amdgcn_mfma_f32_16x16x32_bf16(a, b, c, 0, 0, 0);
}

// 3-way bf16 split of an fp32 value: v ~= s0+s1+s2 to ~2^-25 rel.
__device__ __forceinline__ void split3(float v, __hip_bfloat16& s0,
                                       __hip_bfloat16& s1, __hip_bfloat16& s2) {
    s0 = __float2bfloat16(v);
    float r = v - __bfloat162float(s0);
    s1 = __float2bfloat16(r);
    r -= __bfloat162float(s1);
    s2 = __float2bfloat16(r);
}

// plane-pair schedule for 6-term fp32-emulated product, grouped by A-plane:
// (a,w) = (0,0),(0,1),(0,2),(1,0),(1,1),(2,0) == A-plane g x W-planes 0..(2-g).
// conv_gemm uses pair order (R6 body -- R7/R8 grouping attempts both spilled:
// two-plane weight residency +prefetch exceeds the ~24-reg headroom at 4 w/SIMD).
__device__ __forceinline__ int pair_a(int pp) { return (0x211000 >> (4 * pp)) & 0xF; }
__device__ __forceinline__ int pair_w(int pp) { return (0x010210 >> (4 * pp)) & 0xF; }

// ---------------- prep kernels ----------------

__global__ void prep_scalars_k(
    const float* __restrict__ c1b, const float* __restrict__ g1,
    const float* __restrict__ b1,  const float* __restrict__ m1,
    const float* __restrict__ v1,
    const float* __restrict__ c2b, const float* __restrict__ g2,
    const float* __restrict__ b2,  const float* __restrict__ m2,
    const float* __restrict__ v2,
    const float* __restrict__ c3b, const float* __restrict__ g3,
    const float* __restrict__ b3,  const float* __restrict__ m3,
    const float* __restrict__ v3,
    const float* __restrict__ pfb, const float* __restrict__ vfb,
    const float* __restrict__ mfb,
    float* __restrict__ scale1, float* __restrict__ bias1f,
    float* __restrict__ scale2, float* __restrict__ bias2f,
    float* __restrict__ scale3, float* __restrict__ bias3f,
    float* __restrict__ biasfc)
{
    int t = threadIdx.x;  // 768 threads
    if (t < 64) {
        float s = g1[t] * rsqrtf(v1[t] + 1e-5f);
        scale1[t] = s;
        bias1f[t] = (c1b[t] - m1[t]) * s + b1[t];
    }
    if (t < 128) {
        float s2 = g2[t] * rsqrtf(v2[t] + 1e-5f);
        scale2[t] = s2;
        bias2f[t] = (c2b[t] - m2[t]) * s2 + b2[t];
        float s3 = g3[t] * rsqrtf(v3[t] + 1e-5f);
        scale3[t] = s3;
        bias3f[t] = (c3b[t] - m3[t]) * s3 + b3[t];
    }
    if (t < 256)      biasfc[t] = pfb[t];
    else if (t < 512) biasfc[t] = vfb[t - 256];
    else              biasfc[t] = mfb[t - 512];
}

// conv weights (O, CIN, 3, 3) fp32 -> 3 bf16 planes in FRAG-MAJOR layout:
// dest = kt*4096 + (n>>5)*1024 + ((n>>4)&1)*512 + (kk>>3)*128 + (n&15)*8 + (kk&7)
template<int CIN>
__global__ void prep_convw_k(const float* __restrict__ w,
                             __hip_bfloat16* __restrict__ wt, size_t planeW)
{
    int id = blockIdx.x * 256 + threadIdx.x;
    int kk = id & 31;
    int n  = (id >> 5) & 127;
    int kt = id >> 12;
    int k  = kt * 32 + kk;
    int s  = k / CIN;
    int i  = k & (CIN - 1);
    __hip_bfloat16 s0, s1, s2;
    split3(w[(n * CIN + i) * 9 + s], s0, s1, s2);
    size_t dest = (size_t)kt * 4096 + ((n >> 5) * 1024) + (((n >> 4) & 1) * 512)
                + ((kk >> 3) * 128) + ((n & 15) * 8) + (kk & 7);
    wt[dest] = s0; wt[dest + planeW] = s1; wt[dest + 2 * planeW] = s2;
}

// fused FC1 weight -> 3 bf16 planes, frag-major per 128-col group:
// dest = kt*24576 + (n>>7)*4096 + ((n>>6)&1)*2048 + ((n>>4)&3)*512 + (kk>>3)*128 + (n&15)*8 + (kk&7)
// k' = kt*32+kk = p*128+c ; orig k = c*36+p
__global__ void prep_bigw_k(const float* __restrict__ pw,
                            const float* __restrict__ vw,
                            const float* __restrict__ mw,
                            __hip_bfloat16* __restrict__ bigw, size_t planeBW)
{
    int id = blockIdx.x * 256 + threadIdx.x;   // < 4608*768
    int kk = id & 31;
    int n  = (id >> 5) % 768;
    int kt = id / (32 * 768);
    int k2 = kt * 32 + kk;
    int c  = k2 & 127, p = k2 >> 7;
    int k  = c * 36 + p;
    float v;
    if (n < 256)      v = pw[n * 4608 + k];
    else if (n < 512) v = vw[(n - 256) * 4608 + k];
    else              v = mw[(n - 512) * 4644 + k];
    __hip_bfloat16 s0, s1, s2;
    split3(v, s0, s1, s2);
    size_t dest = (size_t)kt * 24576 + ((n >> 7) * 4096) + (((n >> 6) & 1) * 2048)
                + (((n >> 4) & 3) * 512) + ((kk >> 3) * 128) + ((n & 15) * 8) + (kk & 7);
    bigw[dest] = s0; bigw[dest + planeBW] = s1; bigw[dest + 2 * planeBW] = s2;
}

__global__ void prep_selw_k(const float* __restrict__ mw,
                            float* __restrict__ selw)
{
    int j = blockIdx.x, d = threadIdx.x;
    selw[j * 256 + d] = mw[d * 4644 + 4608 + j];
}

// ---------------- conv1 (4->64, K=36): exact fp32 VALU, split-stored ----------------

__global__ __launch_bounds__(256)
void conv1_k(const float* __restrict__ x,               // (B,4,36) full
             const float* __restrict__ w,               // (64,4,9)
             const float* __restrict__ scale, const float* __restrict__ biasf,
             __hip_bfloat16* __restrict__ out, size_t planeA,  // 3 planes (CH,36,64)
             int b_base)
{
    __shared__ float wl[64 * 37];
    int tid = threadIdx.x;
    for (int c = tid; c < 64 * 36; c += 256) {
        int o = c / 36, k = c - o * 36;
        wl[o * 37 + k] = w[c];
    }
    __syncthreads();
    unsigned gid = blockIdx.x * 256 + tid;  // local (chunk) b*36*64 range
    int o = gid & 63;
    unsigned bp = gid >> 6;                 // local b*36+p
    unsigned b = bp / 36;
    int p = bp - b * 36;
    int py = p / 6, px = p - py * 6;
    const float* xb = x + (size_t)(b_base + b) * 4 * 36;
    float acc = 0.f;
#pragma unroll
    for (int i = 0; i < 4; ++i) {
#pragma unroll
        for (int s = 0; s < 9; ++s) {
            int ny = py + s / 3 - 1, nx = px + s % 3 - 1;
            if ((unsigned)ny < 6u && (unsigned)nx < 6u)
                acc += xb[i * 36 + ny * 6 + nx] * wl[o * 37 + i * 9 + s];
        }
    }
    float v = fmaxf(acc * scale[o] + biasf[o], 0.f);
    __hip_bfloat16 s0, s1, s2;
    split3(v, s0, s1, s2);
    size_t idx = (size_t)bp * 64 + o;
    out[idx] = s0; out[idx + planeA] = s1; out[idx + 2 * planeA] = s2;
}

// ---------------- conv2/conv3: implicit-im2col MFMA GEMM, 6-term fp32-emulated ----------------
// R10 = R6 body + issue-slot diet (MfmaUtil+VALUBusy = 98% -> sequencer-bound):
// (a) shift-invariant im2col geometry hoisted (pyr/pxr/P0, +15 VGPR -> 119/128
//     unified budget at 4 waves/SIMD; R7's spill was +36 on top of this);
// (b) prefetch clamp dropped -- weight buffers have one kt-slice of pad so the
//     last iteration's prefetch reads discarded pad instead of cmp+cndmask.
template<int CIN>
__global__ __launch_bounds__(256, 4)
void conv_gemm_k(const __hip_bfloat16* __restrict__ in, size_t planeA,   // 3 planes (CH,36,CIN)
                 const __hip_bfloat16* __restrict__ wt, size_t planeW,   // 3 planes frag-major [K/32][4096] (+1 slice pad)
                 const float* __restrict__ scale,
                 const float* __restrict__ biasf,
                 __hip_bfloat16* __restrict__ out, size_t planeO)        // 3 planes (CH,36,128)
{
    constexpr int PS  = CIN + 8;
    constexpr int CPB = CIN / 32;
    constexpr int NSLICE = CPB * 9;
    constexpr int XS_ELEMS = 72 * PS;
    __shared__ __align__(16) __hip_bfloat16 smem[XS_ELEMS + CIN];  // xs + zero region
    __hip_bfloat16* xs = smem;

    const int tid  = threadIdx.x;
    const int wave = tid >> 6, lane = tid & 63;
    const int m16  = lane & 15, quad = lane >> 4;
    const int b0   = blockIdx.x * 2;   // local image index (2 images/block)

    if (tid < CIN) smem[XS_ELEMS + tid] = __float2bfloat16(0.f);  // SAME-pad zeros

    f32x4 acc[5][2];
#pragma unroll
    for (int i = 0; i < 5; ++i) { acc[i][0] = f32x4{0,0,0,0}; acc[i][1] = f32x4{0,0,0,0}; }

    const int bo0 = wave * 1024 + lane * 8;          // ct=0 frag (elems)
    const int bo1 = bo0 + 512;                       // ct=1 frag
    const int sent = XS_ELEMS + quad * 8;            // zero-region aoff

    // hoisted per-rt geometry (shift-invariant): pyr/pxr/P0. Invalid rows
    // (rt=4, m16>=8) get pyr=pxr=100 so every bounds test fails -> sent.
    int pyr[5], pxr[5], P0[5];
#pragma unroll
    for (int rt = 0; rt < 5; ++rt) {
        int m   = rt * 16 + m16;          // 0..79; valid < 72
        int img = m >= 36;
        int p   = m - img * 36;
        int py  = p / 6, px = p - py * 6;
        bool v  = (m < 72);
        pyr[rt] = v ? py : 100;
        pxr[rt] = v ? px : 100;
        P0[rt]  = (img * 36 + py * 6 + px) * PS + quad * 8;
    }

    constexpr int CHPP = CIN / 8;
    for (int pp = 0; pp < 6; ++pp) {
        const __hip_bfloat16* inb = in + (size_t)pair_a(pp) * planeA + (size_t)b0 * 36 * CIN;
        const __hip_bfloat16* wP  = wt + (size_t)pair_w(pp) * planeW;
        const bool stage_x = (pp == 0) || (pair_a(pp) != pair_a(pp - 1));

        if (stage_x) {   // block-uniform; only 3 of 6 passes
            __syncthreads();   // all waves done reading previous xs (covers zs init at pp=0)
            for (int c = tid; c < 72 * CHPP; c += 256) {
                int pix = c / CHPP;
                int off = (c - pix * CHPP) * 8;
                *(int4v*)(xs + pix * PS + off) = *(const int4v*)(inb + pix * CIN + off);
            }
            __syncthreads();
        }

        // per-pass prologue: load this wave's kt=0 weight frags straight to VGPRs
        bf16x8 wc0 = *(const bf16x8*)(wP + bo0);
        bf16x8 wc1 = *(const bf16x8*)(wP + bo1);

        for (int s = 0; s < 9; ++s) {
            const int dy = s / 3 - 1, dx = s % 3 - 1;
            const int soff = (dy * 6 + dx) * PS;     // wave-uniform (SGPR)
            int aoff[5];
#pragma unroll
            for (int rt = 0; rt < 5; ++rt) {
                int ny = pyr[rt] + dy, nx = pxr[rt] + dx;
                bool ok = ((unsigned)ny < 6u) && ((unsigned)nx < 6u);
                aoff[rt] = ok ? (P0[rt] + soff) : sent;
            }
#pragma unroll
            for (int c = 0; c < CPB; ++c) {
                const int kt = s * CPB + c;
                // unconditional next-slice prefetch: last kt reads the pad
                // slice (discarded) -- no clamp cmp/cndmask.
                const __hip_bfloat16* wN = wP + (size_t)(kt + 1) * 4096;
                bf16x8 wn0 = *(const bf16x8*)(wN + bo0);
                bf16x8 wn1 = *(const bf16x8*)(wN + bo1);
                const int coff = c * 32;
#pragma unroll
                for (int rt = 0; rt < 5; ++rt) {
                    bf16x8 af = *(const bf16x8*)(smem + aoff[rt] + coff);
                    acc[rt][0] = mfma16(af, wc0, acc[rt][0]);
                    acc[rt][1] = mfma16(af, wc1, acc[rt][1]);
                }
                wc0 = wn0; wc1 = wn1;
            }
        }
    }

    // epilogue: fused BN scale/bias + relu, split-store 3 bf16 planes
#pragma unroll
    for (int ct = 0; ct < 2; ++ct) {
        const int n = wave * 32 + ct * 16 + m16;
        const float sc = scale[n], bi = biasf[n];
#pragma unroll
        for (int rt = 0; rt < 5; ++rt) {
            const int mrow = rt * 16 + quad * 4;
            if (mrow < 72) {
#pragma unroll
                for (int r = 0; r < 4; ++r) {
                    float v = fmaxf(acc[rt][ct][r] * sc + bi, 0.f);
                    __hip_bfloat16 s0, s1, s2;
                    split3(v, s0, s1, s2);
                    size_t idx = (size_t)(b0 * 36 + mrow + r) * 128 + n;
                    out[idx] = s0; out[idx + planeO] = s1; out[idx + 2 * planeO] = s2;
                }
            }
        }
    }
}

// ---------------- FC1 partial GEMM: A-plane grouped, runtime K-split ----------------
// All NS partial slots are summed in heads_k, so a block accumulates several
// plane-pairs into ONE acc. g0 = A0 x {W0,W1,W2}, g1 = A1 x {W0,W1}, g2 = A2 x {W0}.
// NS=12 at both chunk sizes (even 9 blocks/CU at CH=4096). R10: prefetch clamps
// dropped (over-reads land in adjacent mapped ws arrays, values discarded).

template<int NW>
__device__ __forceinline__ void fc_body(
    const __hip_bfloat16* __restrict__ Ap,    // A-plane base (g applied)
    const __hip_bfloat16* __restrict__ Bp,    // Bw + nblk*4096 (W-plane 0)
    size_t planeBW, int kt0, int NKT,
    float* __restrict__ outp, size_t m0,
    __hip_bfloat16* smem, int tid, int wave, int lane)
{
    constexpr int ABUF = 4096;
    const int m16 = lane & 15, quad = lane >> 4;
    const int wr = wave >> 1, wc = wave & 1;
    const int cr = tid >> 2, co = (tid & 3) * 8;

    f32x4 acc[4][4];
#pragma unroll
    for (int i = 0; i < 4; ++i)
#pragma unroll
        for (int j = 0; j < 4; ++j) acc[i][j] = f32x4{0,0,0,0};

    int ao[4];
#pragma unroll
    for (int i = 0; i < 4; ++i) ao[i] = wr * 2048 + i * 512 + lane * 8;
    const int bofs = wc * 2048 + lane * 8;
    const int adst = ((cr >> 4) & 3) * 512 + (tid & 3) * 128 + (cr & 15) * 8;

    auto ldA = [&](int ktr, int4v& a0, int4v& a1) {   // ktr relative to kt0
        const __hip_bfloat16* base = Ap + (m0 + cr) * 4608 + (kt0 + ktr) * 32 + co;
        a0 = *(const int4v*)base;
        a1 = *(const int4v*)(base + (size_t)64 * 4608);
    };
    auto ldB = [&](int p, bf16x8* bf) {               // phase p -> (ktr, w)
        const int ktr = p / NW, w = p - ktr * NW;
        const __hip_bfloat16* base = Bp + (size_t)w * planeBW
                                   + (size_t)(kt0 + ktr) * 24576 + bofs;
#pragma unroll
        for (int i = 0; i < 4; ++i) bf[i] = *(const bf16x8*)(base + i * 512);
    };
    auto stA = [&](int buf, int4v a0, int4v a1) {
        __hip_bfloat16* base = smem + buf * ABUF;
        *(int4v*)(base + adst) = a0;                  // rows 0..63
        *(int4v*)(base + 2048 + adst) = a1;           // rows 64..127
    };

    // prologue
    int4v pa0, pa1, qa0, qa1;
    bf16x8 Bc[4], B1[4], Bn[4];
    {
        int4v a0, a1;
        ldA(0, a0, a1);
        ldB(0, Bc);
        ldA(1, pa0, pa1);
        ldB(1, B1);
        stA(0, a0, a1);
    }
    __syncthreads();
    int cur = 0;

#pragma unroll 2
    for (int ktr = 0; ktr < NKT; ++ktr) {
        // A prefetch, 2-kt slack; unconditional (tail over-read ~80B into the
        // next mapped ws array, discarded)
        ldA(ktr + 2, qa0, qa1);
        // A fragments for this kt, shared across all NW B-phases
        const __hip_bfloat16* base = smem + cur * ABUF;
        bf16x8 af[4];
#pragma unroll
        for (int i = 0; i < 4; ++i) af[i] = *(const bf16x8*)(base + ao[i]);
#pragma unroll
        for (int w = 0; w < NW; ++w) {
            ldB(ktr * NW + w + 2, Bn);                // unconditional (pad-read at tail)
#pragma unroll
            for (int i = 0; i < 4; ++i)
#pragma unroll
                for (int j = 0; j < 4; ++j)
                    acc[i][j] = mfma16(af[i], Bc[j], acc[i][j]);
#pragma unroll
            for (int i = 0; i < 4; ++i) { Bc[i] = B1[i]; B1[i] = Bn[i]; }
        }
        if (ktr + 1 < NKT) stA(cur ^ 1, pa0, pa1);    // waits loads issued last kt
        __syncthreads();
        cur ^= 1;
        pa0 = qa0; pa1 = qa1;
    }

#pragma unroll
    for (int i = 0; i < 4; ++i) {
        const int row = wr * 64 + i * 16 + quad * 4;
#pragma unroll
        for (int j = 0; j < 4; ++j) {
            const int col = wc * 64 + j * 16 + m16;
#pragma unroll
            for (int r = 0; r < 4; ++r)
                outp[(m0 + row + r) * 768 + col] = acc[i][j][r];
        }
    }
}

__global__ __launch_bounds__(256, 3)
void fc_partial_k(const __hip_bfloat16* __restrict__ A, size_t planeF,    // 3 planes (CH,4608)
                  const __hip_bfloat16* __restrict__ Bw, size_t planeBW,  // 3 planes frag-major [144][24576]
                  float* __restrict__ partial,                            // [NS](CH,768)
                  int chunk, int ns6)
{
    constexpr int ABUF = 4096;
    __shared__ __align__(16) __hip_bfloat16 smem[2 * ABUF];   // 16 KB
    const int tid = threadIdx.x, wave = tid >> 6, lane = tid & 63;
    const int nmblk = chunk >> 7;
    const int mblk = blockIdx.x & (nmblk - 1);
    int rest = blockIdx.x / nmblk;
    const int nblk = rest % 6;
    const int slot = rest / 6;
    const size_t m0 = (size_t)mblk * 128;

    const __hip_bfloat16* Bp = Bw + (size_t)nblk * 4096;
    float* outp = partial + (size_t)slot * chunk * 768 + (size_t)nblk * 128;

    if (ns6) {   // NS=6: g0 slots 0-2 (NKT 48), g1 slots 3-4 (72), g2 slot 5 (144)
        if (slot < 3)
            fc_body<3>(A, Bp, planeBW, slot * 48, 48, outp, m0, smem, tid, wave, lane);
        else if (slot < 5)
            fc_body<2>(A + planeF, Bp, planeBW, (slot - 3) * 72, 72, outp, m0, smem, tid, wave, lane);
        else
            fc_body<1>(A + 2 * planeF, Bp, planeBW, 0, 144, outp, m0, smem, tid, wave, lane);
    } else {     // NS=12: g0 slots 0-5 (24), g1 slots 6-9 (36), g2 slots 10-11 (72)
        if (slot < 6)
            fc_body<3>(A, Bp, planeBW, slot * 24, 24, outp, m0, smem, tid, wave, lane);
        else if (slot < 10)
            fc_body<2>(A + planeF, Bp, planeBW, (slot - 6) * 36, 36, outp, m0, smem, tid, wave, lane);
        else
            fc_body<1>(A + 2 * planeF, Bp, planeBW, (slot - 10) * 72, 72, outp, m0, smem, tid, wave, lane);
    }
}

// ---------------- heads: partial-sum + LN + small GEMVs + argmax + dueling (fp32) ----------------

__global__ __launch_bounds__(256)
void heads_k(const float* __restrict__ partial,          // [ns](CH,768): [piece|value|move]
             const float* __restrict__ biasfc,           // 768
             const float* __restrict__ pln_g, const float* __restrict__ pln_b,
             const float* __restrict__ pfc2_w, const float* __restrict__ pfc2_b,
             const float* __restrict__ mln_g, const float* __restrict__ mln_b,
             const float* __restrict__ mfc2_w, const float* __restrict__ mfc2_b,
             const float* __restrict__ vln_g, const float* __restrict__ vln_b,
             const float* __restrict__ vfc2_w, const float* __restrict__ vfc2_b,
             const float* __restrict__ selw,             // (36,256)
             float* __restrict__ q,                      // (B,1296) full
             int b_base, int ns, int chunk)
{
    __shared__ float hp[256], hv[256], hm[256];
    __shared__ float pl[36], ml[36];
    __shared__ float red[4];
    __shared__ float valv, plm_s, mlm_s;
    __shared__ int amax_s;

    const int tid = threadIdx.x, wave = tid >> 6, lane = tid & 63;
    const size_t b = blockIdx.x;                // local
    const size_t bg = b_base + b;               // global

    // inline fc-reduce: sum ns partials + bias
    float pp = biasfc[tid], vv = biasfc[256 + tid], mm = biasfc[512 + tid];
    for (int k = 0; k < ns; ++k) {
        const float* row = partial + (size_t)k * chunk * 768 + b * 768;
        pp += row[tid]; vv += row[256 + tid]; mm += row[512 + tid];
    }

    auto warpSum = [&](float v) {
        v += __shfl_xor(v, 1);  v += __shfl_xor(v, 2);  v += __shfl_xor(v, 4);
        v += __shfl_xor(v, 8);  v += __shfl_xor(v, 16); v += __shfl_xor(v, 32);
        return v;
    };
    auto blockSum = [&](float v) {
        v = warpSum(v);
        if (lane == 0) red[wave] = v;
        __syncthreads();
        float s = red[0] + red[1] + red[2] + red[3];
        __syncthreads();
        return s;
    };
    auto lnrelu = [&](float x, const float* g, const float* bb) {
        float mu  = blockSum(x) * (1.f / 256.f);
        float d   = x - mu;
        float var = blockSum(d * d) * (1.f / 256.f);
        float y   = d * rsqrtf(var + 1e-5f) * g[tid] + bb[tid];
        return fmaxf(y, 0.f);
    };

    hp[tid] = lnrelu(pp, pln_g, pln_b);
    hv[tid] = lnrelu(vv, vln_g, vln_b);
    __syncthreads();

    {
        float h0 = hp[lane], h1 = hp[64 + lane], h2 = hp[128 + lane], h3 = hp[192 + lane];
#pragma unroll
        for (int jj = 0; jj < 9; ++jj) {
            int j = wave * 9 + jj;
            const float* wr_ = pfc2_w + j * 256;
            float s = h0 * wr_[lane] + h1 * wr_[64 + lane]
                    + h2 * wr_[128 + lane] + h3 * wr_[192 + lane];
            s = warpSum(s);
            if (lane == 0) pl[j] = s + pfc2_b[j];
        }
        if (wave == 0) {
            float g0 = hv[lane], g1 = hv[64 + lane], g2 = hv[128 + lane], g3 = hv[192 + lane];
            float s = g0 * vfc2_w[lane] + g1 * vfc2_w[64 + lane]
                    + g2 * vfc2_w[128 + lane] + g3 * vfc2_w[192 + lane];
            s = warpSum(s);
            if (lane == 0) valv = s + vfc2_b[0];
        }
    }
    __syncthreads();
    if (tid == 0) {   // first-max argmax (jnp semantics) + mean
        float m = -1e30f, s = 0.f; int idx = 0;
        for (int j = 0; j < 36; ++j) { float v = pl[j]; s += v; if (v > m) { m = v; idx = j; } }
        plm_s = s * (1.f / 36.f); amax_s = idx;
    }
    __syncthreads();

    mm += selw[amax_s * 256 + tid];   // one-hot concat == single column add
    hm[tid] = lnrelu(mm, mln_g, mln_b);
    __syncthreads();
    {
        float h0 = hm[lane], h1 = hm[64 + lane], h2 = hm[128 + lane], h3 = hm[192 + lane];
#pragma unroll
        for (int jj = 0; jj < 9; ++jj) {
            int j = wave * 9 + jj;
            const float* wr_ = mfc2_w + j * 256;
            float s = h0 * wr_[lane] + h1 * wr_[64 + lane]
                    + h2 * wr_[128 + lane] + h3 * wr_[192 + lane];
            s = warpSum(s);
            if (lane == 0) ml[j] = s + mfc2_b[j];
        }
    }
    __syncthreads();
    if (tid == 0) {
        float s = 0.f;
        for (int j = 0; j < 36; ++j) s += ml[j];
        mlm_s = s * (1.f / 36.f);
    }
    __syncthreads();

    const float val = valv, plm = plm_s, mlm = mlm_s;
    for (int idx = tid; idx < 1296; idx += 256) {
        int i = idx / 36, j = idx - i * 36;
        q[bg * 1296 + idx] = val + (pl[i] - plm) + (ml[j] - mlm);
    }
}

// ---------------- launch ----------------

extern "C" void kernel_launch(void* const* d_in, const int* in_sizes, int n_in,
                              void* d_out, int out_size, void* d_ws, size_t ws_size,
                              hipStream_t stream)
{
    const float* x       = (const float*)d_in[0];
    const float* conv1_w = (const float*)d_in[1];
    const float* conv1_b = (const float*)d_in[2];
    const float* bn1_g   = (const float*)d_in[3];
    const float* bn1_b   = (const float*)d_in[4];
    const float* bn1_m   = (const float*)d_in[5];
    const float* bn1_v   = (const float*)d_in[6];
    const float* conv2_w = (const float*)d_in[7];
    const float* conv2_b = (const float*)d_in[8];
    const float* bn2_g   = (const float*)d_in[9];
    const float* bn2_b   = (const float*)d_in[10];
    const float* bn2_m   = (const float*)d_in[11];
    const float* bn2_v   = (const float*)d_in[12];
    const float* conv3_w = (const float*)d_in[13];
    const float* conv3_b = (const float*)d_in[14];
    const float* bn3_g   = (const float*)d_in[15];
    const float* bn3_b   = (const float*)d_in[16];
    const float* bn3_m   = (const float*)d_in[17];
    const float* bn3_v   = (const float*)d_in[18];
    const float* pfc1_w  = (const float*)d_in[19];
    const float* pfc1_b  = (const float*)d_in[20];
    const float* pln_g   = (const float*)d_in[21];
    const float* pln_b   = (const float*)d_in[22];
    const float* pfc2_w  = (const float*)d_in[23];
    const float* pfc2_b  = (const float*)d_in[24];
    const float* mfc1_w  = (const float*)d_in[25];
    const float* mfc1_b  = (const float*)d_in[26];
    const float* mln_g   = (const float*)d_in[27];
    const float* mln_b   = (const float*)d_in[28];
    const float* mfc2_w  = (const float*)d_in[29];
    const float* mfc2_b  = (const float*)d_in[30];
    const float* vfc1_w  = (const float*)d_in[31];
    const float* vfc1_b  = (const float*)d_in[32];
    const float* vln_g   = (const float*)d_in[33];
    const float* vln_b   = (const float*)d_in[34];
    const float* vfc2_w  = (const float*)d_in[35];
    const float* vfc2_b  = (const float*)d_in[36];

    const size_t planeW2 = 576 * 128;               // conv2 weight plane elems
    const size_t planeW3 = 1152 * 128;              // conv3 weight plane elems
    const size_t planeBW = (size_t)4608 * 768;      // fc weight plane elems
    const size_t WPAD    = 4096 * 2;                // one kt-slice pad (bytes) for clamp-free prefetch

    // workspace layout size for a given (chunk, n_slots)
    auto layout_total = [&](int CHv, int NSv) -> size_t {
        size_t t = 0;
        auto add = [&](size_t b) { t += (b + 255) & ~(size_t)255; };
        add(3 * planeW2 * 2 + WPAD); add(3 * planeW3 * 2 + WPAD); add(3 * planeBW * 2);
        add(36 * 256 * 4);
        add(64 * 4); add(64 * 4); add(128 * 4); add(128 * 4);
        add(128 * 4); add(128 * 4); add(768 * 4);
        size_t pA2 = (size_t)CHv * 36 * 128;
        add(3 * pA2 * 2);                                      // A1
        size_t par = (size_t)NSv * CHv * 768 * 4;
        add((3 * pA2 * 2 > par) ? 3 * pA2 * 2 : par);          // A2
        return t;
    };

    // 3-tier runtime config: prefer CH=4096 + NS=12 (~287 MB; fc grid 2304 =
    // 9 blocks/CU), else CH=4096 + NS=6 (~249 MB, proven to fit in R6/R8),
    // else the proven CH=2048/12 config.
    int CH, NS;
    if (layout_total(4096, 12) <= ws_size)     { CH = 4096; NS = 12; }
    else if (layout_total(4096, 6) <= ws_size) { CH = 4096; NS = 6;  }
    else                                       { CH = 2048; NS = 12; }
    const int ns6 = (NS == 6);
    const int NCH = BQ / CH;

    const size_t planeA1 = (size_t)CH * 36 * 64;
    const size_t planeA2 = (size_t)CH * 36 * 128;

    char* ws = (char*)d_ws;
    size_t off = 0;
    auto alloc = [&](size_t bytes) -> char* {
        char* p = ws + off; off += (bytes + 255) & ~(size_t)255; return p;
    };
    __hip_bfloat16* w2t  = (__hip_bfloat16*)alloc(3 * planeW2 * 2 + WPAD);
    __hip_bfloat16* w3t  = (__hip_bfloat16*)alloc(3 * planeW3 * 2 + WPAD);
    __hip_bfloat16* bigw = (__hip_bfloat16*)alloc(3 * planeBW * 2);
    float* selw   = (float*)alloc(36 * 256 * 4);
    float* scale1 = (float*)alloc(64 * 4);
    float* bias1f = (float*)alloc(64 * 4);
    float* scale2 = (float*)alloc(128 * 4);
    float* bias2f = (float*)alloc(128 * 4);
    float* scale3 = (float*)alloc(128 * 4);
    float* bias3f = (float*)alloc(128 * 4);
    float* biasfc = (float*)alloc(768 * 4);
    // ping-pong arenas, per-chunk: A1: h1 -> h3 ; A2: h2 -> fc partials
    size_t parBytes = (size_t)NS * CH * 768 * 4;
    char* A1 = alloc(3 * planeA2 * 2);
    char* A2 = alloc((3 * planeA2 * 2 > parBytes) ? 3 * planeA2 * 2 : parBytes);

    prep_scalars_k<<<1, 768, 0, stream>>>(
        conv1_b, bn1_g, bn1_b, bn1_m, bn1_v,
        conv2_b, bn2_g, bn2_b, bn2_m, bn2_v,
        conv3_b, bn3_g, bn3_b, bn3_m, bn3_v,
        pfc1_b, vfc1_b, mfc1_b,
        scale1, bias1f, scale2, bias2f, scale3, bias3f, biasfc);
    prep_convw_k<64><<<288, 256, 0, stream>>>(conv2_w, w2t, planeW2);
    prep_convw_k<128><<<576, 256, 0, stream>>>(conv3_w, w3t, planeW3);
    prep_bigw_k<<<13824, 256, 0, stream>>>(pfc1_w, vfc1_w, mfc1_w, bigw, planeBW);
    prep_selw_k<<<36, 256, 0, stream>>>(mfc1_w, selw);

    __hip_bfloat16* h1s  = (__hip_bfloat16*)A1;
    __hip_bfloat16* h2s  = (__hip_bfloat16*)A2;
    __hip_bfloat16* h3s  = (__hip_bfloat16*)A1;   // overwrites h1s (dead after conv2)
    float*          fpar = (float*)A2;            // overwrites h2s (dead after conv3)

    for (int cchunk = 0; cchunk < NCH; ++cchunk) {
        const int b_base = cchunk * CH;
        conv1_k<<<CH * 9, 256, 0, stream>>>(
            x, conv1_w, scale1, bias1f, h1s, planeA1, b_base);
        conv_gemm_k<64><<<CH / 2, 256, 0, stream>>>(
            h1s, planeA1, w2t, planeW2, scale2, bias2f, h2s, planeA2);
        conv_gemm_k<128><<<CH / 2, 256, 0, stream>>>(
            h2s, planeA2, w3t, planeW3, scale3, bias3f, h3s, planeA2);
        fc_partial_k<<<(CH / 128) * 6 * NS, 256, 0, stream>>>(
            h3s, planeA2, bigw, planeBW, fpar, CH, ns6);
        heads_k<<<CH, 256, 0, stream>>>(fpar, biasfc,
            pln_g, pln_b, pfc2_w, pfc2_b,
            mln_g, mln_b, mfc2_w, mfc2_b,
            vln_g, vln_b, vfc2_w, vfc2_b,
            selw, (float*)d_out, b_base, NS, CH);
    }
}

// Round 11
// 1588.805 us; speedup vs baseline: 1.0288x; 1.0288x over previous
//
#include <hip/hip_runtime.h>
#include <hip/hip_bf16.h>

#define BQ 8192
typedef __attribute__((ext_vector_type(8))) __bf16 bf16x8;
typedef __attribute__((ext_vector_type(4))) float f32x4;
typedef __attribute__((ext_vector_type(4))) int int4v;

__device__ __forceinline__ f32x4 mfma16(bf16x8 a, bf16x8 b, f32x4 c) {
    return __builtin_amdgcn_mfma_f32_16x16x32_bf16(a, b, c, 0, 0, 0);
}

// 3-way bf16 split of an fp32 value: v ~= s0+s1+s2 to ~2^-25 rel.
__device__ __forceinline__ void split3(float v, __hip_bfloat16& s0,
                                       __hip_bfloat16& s1, __hip_bfloat16& s2) {
    s0 = __float2bfloat16(v);
    float r = v - __bfloat162float(s0);
    s1 = __float2bfloat16(r);
    r -= __bfloat162float(s1);
    s2 = __float2bfloat16(r);
}

// 6-term fp32-emulated product, grouped by A-plane:
// pairs = A-plane g x W-planes 0..(2-g). conv passes: (A0x{W0,W1}),(A0x{W2}),
// (A1x{W0,W1}),(A2x{W0}); fc uses grouped slots.

// ---------------- prep kernels ----------------

__global__ void prep_scalars_k(
    const float* __restrict__ c1b, const float* __restrict__ g1,
    const float* __restrict__ b1,  const float* __restrict__ m1,
    const float* __restrict__ v1,
    const float* __restrict__ c2b, const float* __restrict__ g2,
    const float* __restrict__ b2,  const float* __restrict__ m2,
    const float* __restrict__ v2,
    const float* __restrict__ c3b, const float* __restrict__ g3,
    const float* __restrict__ b3,  const float* __restrict__ m3,
    const float* __restrict__ v3,
    const float* __restrict__ pfb, const float* __restrict__ vfb,
    const float* __restrict__ mfb,
    float* __restrict__ scale1, float* __restrict__ bias1f,
    float* __restrict__ scale2, float* __restrict__ bias2f,
    float* __restrict__ scale3, float* __restrict__ bias3f,
    float* __restrict__ biasfc)
{
    int t = threadIdx.x;  // 768 threads
    if (t < 64) {
        float s = g1[t] * rsqrtf(v1[t] + 1e-5f);
        scale1[t] = s;
        bias1f[t] = (c1b[t] - m1[t]) * s + b1[t];
    }
    if (t < 128) {
        float s2 = g2[t] * rsqrtf(v2[t] + 1e-5f);
        scale2[t] = s2;
        bias2f[t] = (c2b[t] - m2[t]) * s2 + b2[t];
        float s3 = g3[t] * rsqrtf(v3[t] + 1e-5f);
        scale3[t] = s3;
        bias3f[t] = (c3b[t] - m3[t]) * s3 + b3[t];
    }
    if (t < 256)      biasfc[t] = pfb[t];
    else if (t < 512) biasfc[t] = vfb[t - 256];
    else              biasfc[t] = mfb[t - 512];
}

// conv weights (O, CIN, 3, 3) fp32 -> 3 bf16 planes in FRAG-MAJOR layout:
// dest = kt*4096 + (n>>5)*1024 + ((n>>4)&1)*512 + (kk>>3)*128 + (n&15)*8 + (kk&7)
template<int CIN>
__global__ void prep_convw_k(const float* __restrict__ w,
                             __hip_bfloat16* __restrict__ wt, size_t planeW)
{
    int id = blockIdx.x * 256 + threadIdx.x;
    int kk = id & 31;
    int n  = (id >> 5) & 127;
    int kt = id >> 12;
    int k  = kt * 32 + kk;
    int s  = k / CIN;
    int i  = k & (CIN - 1);
    __hip_bfloat16 s0, s1, s2;
    split3(w[(n * CIN + i) * 9 + s], s0, s1, s2);
    size_t dest = (size_t)kt * 4096 + ((n >> 5) * 1024) + (((n >> 4) & 1) * 512)
                + ((kk >> 3) * 128) + ((n & 15) * 8) + (kk & 7);
    wt[dest] = s0; wt[dest + planeW] = s1; wt[dest + 2 * planeW] = s2;
}

// fused FC1 weight -> 3 bf16 planes, frag-major per 128-col group:
// dest = kt*24576 + (n>>7)*4096 + ((n>>6)&1)*2048 + ((n>>4)&3)*512 + (kk>>3)*128 + (n&15)*8 + (kk&7)
// k' = kt*32+kk = p*128+c ; orig k = c*36+p
__global__ void prep_bigw_k(const float* __restrict__ pw,
                            const float* __restrict__ vw,
                            const float* __restrict__ mw,
                            __hip_bfloat16* __restrict__ bigw, size_t planeBW)
{
    int id = blockIdx.x * 256 + threadIdx.x;   // < 4608*768
    int kk = id & 31;
    int n  = (id >> 5) % 768;
    int kt = id / (32 * 768);
    int k2 = kt * 32 + kk;
    int c  = k2 & 127, p = k2 >> 7;
    int k  = c * 36 + p;
    float v;
    if (n < 256)      v = pw[n * 4608 + k];
    else if (n < 512) v = vw[(n - 256) * 4608 + k];
    else              v = mw[(n - 512) * 4644 + k];
    __hip_bfloat16 s0, s1, s2;
    split3(v, s0, s1, s2);
    size_t dest = (size_t)kt * 24576 + ((n >> 7) * 4096) + (((n >> 6) & 1) * 2048)
                + (((n >> 4) & 3) * 512) + ((kk >> 3) * 128) + ((n & 15) * 8) + (kk & 7);
    bigw[dest] = s0; bigw[dest + planeBW] = s1; bigw[dest + 2 * planeBW] = s2;
}

__global__ void prep_selw_k(const float* __restrict__ mw,
                            float* __restrict__ selw)
{
    int j = blockIdx.x, d = threadIdx.x;
    selw[j * 256 + d] = mw[d * 4644 + 4608 + j];
}

// ---------------- conv1 (4->64, K=36): exact fp32 VALU, split-stored ----------------

__global__ __launch_bounds__(256)
void conv1_k(const float* __restrict__ x,               // (B,4,36) full
             const float* __restrict__ w,               // (64,4,9)
             const float* __restrict__ scale, const float* __restrict__ biasf,
             __hip_bfloat16* __restrict__ out, size_t planeA,  // 3 planes (CH,36,64)
             int b_base)
{
    __shared__ float wl[64 * 37];
    int tid = threadIdx.x;
    for (int c = tid; c < 64 * 36; c += 256) {
        int o = c / 36, k = c - o * 36;
        wl[o * 37 + k] = w[c];
    }
    __syncthreads();
    unsigned gid = blockIdx.x * 256 + tid;  // local (chunk) b*36*64 range
    int o = gid & 63;
    unsigned bp = gid >> 6;                 // local b*36+p
    unsigned b = bp / 36;
    int p = bp - b * 36;
    int py = p / 6, px = p - py * 6;
    const float* xb = x + (size_t)(b_base + b) * 4 * 36;
    float acc = 0.f;
#pragma unroll
    for (int i = 0; i < 4; ++i) {
#pragma unroll
        for (int s = 0; s < 9; ++s) {
            int ny = py + s / 3 - 1, nx = px + s % 3 - 1;
            if ((unsigned)ny < 6u && (unsigned)nx < 6u)
                acc += xb[i * 36 + ny * 6 + nx] * wl[o * 37 + i * 9 + s];
        }
    }
    float v = fmaxf(acc * scale[o] + biasf[o], 0.f);
    __hip_bfloat16 s0, s1, s2;
    split3(v, s0, s1, s2);
    size_t idx = (size_t)bp * 64 + o;
    out[idx] = s0; out[idx + planeA] = s1; out[idx + 2 * planeA] = s2;
}

// ---------------- conv2/conv3: implicit-im2col MFMA GEMM, pair-grouped, single-buffered W ----------------
// R11: LDS-BW is the measured wall (320 cyc/kt ideal == 324 measured). Grouped
// passes (A0x{W0,W1}),(A0x{W2}),(A1x{W0,W1}),(A2x{W0}) cut per-wave LDS A-reads
// 1080 -> 720 (floor 320 -> 213 cyc). Register discipline (R3/R7/R8 lesson:
// every dbuf variant spilled): NO weight prefetch. Per kt: load current 2-plane
// frags (32 VGPR, single-buffered), then per rt {1 LDS read, 4 MFMA}. WAR on
// MFMA-issue lets next-kt loads issue immediately; 4 barrier-free waves/SIMD
// hide the ~200cyc L2 latency. ~75 VGPR + 40 AGPR = 115 <= 128 @ 4 waves/SIMD.
// Geometry stays R9's in-loop form (R10 hoist regressed).
template<int CIN, int NW>
__device__ __forceinline__ void conv_pass(
    const __hip_bfloat16* __restrict__ smem,
    const __hip_bfloat16* __restrict__ wt,        // base of first W-plane of this pass
    size_t planeW, f32x4 (&acc)[5][2],
    int m16, int quad, int bo0, int bo1)
{
    constexpr int PS  = CIN + 8;
    constexpr int CPB = CIN / 32;
    constexpr int XS_ELEMS = 72 * PS;

    for (int s = 0; s < 9; ++s) {
        const int dy = s / 3 - 1, dx = s % 3 - 1;
        int aoff[5];
#pragma unroll
        for (int rt = 0; rt < 5; ++rt) {
            int m   = rt * 16 + m16;          // 0..79; valid < 72
            int img = m >= 36;
            int p   = m - img * 36;
            int py  = p / 6, px = p - py * 6;
            int ny  = py + dy, nx = px + dx;
            bool ok = (m < 72) && ((unsigned)ny < 6u) && ((unsigned)nx < 6u);
            int base = ok ? ((img * 36 + ny * 6 + nx) * PS) : XS_ELEMS;
            aoff[rt] = base + quad * 8;
        }
#pragma unroll
        for (int c = 0; c < CPB; ++c) {
            const int kt = s * CPB + c;
            const __hip_bfloat16* wK = wt + (size_t)kt * 4096;
            // single-buffered weight load for THIS kt (no prefetch regs)
            bf16x8 a0 = *(const bf16x8*)(wK + bo0);
            bf16x8 a1 = *(const bf16x8*)(wK + bo1);
            bf16x8 b0, b1;
            if (NW == 2) {
                b0 = *(const bf16x8*)(wK + planeW + bo0);
                b1 = *(const bf16x8*)(wK + planeW + bo1);
            }
            const int coff = c * 32;
#pragma unroll
            for (int rt = 0; rt < 5; ++rt) {
                bf16x8 af = *(const bf16x8*)(smem + aoff[rt] + coff);
                acc[rt][0] = mfma16(af, a0, acc[rt][0]);
                acc[rt][1] = mfma16(af, a1, acc[rt][1]);
                if (NW == 2) {
                    acc[rt][0] = mfma16(af, b0, acc[rt][0]);
                    acc[rt][1] = mfma16(af, b1, acc[rt][1]);
                }
            }
        }
    }
}

template<int CIN>
__global__ __launch_bounds__(256, 4)
void conv_gemm_k(const __hip_bfloat16* __restrict__ in, size_t planeA,   // 3 planes (CH,36,CIN)
                 const __hip_bfloat16* __restrict__ wt, size_t planeW,   // 3 planes frag-major [K/32][4096]
                 const float* __restrict__ scale,
                 const float* __restrict__ biasf,
                 __hip_bfloat16* __restrict__ out, size_t planeO)        // 3 planes (CH,36,128)
{
    constexpr int PS  = CIN + 8;
    constexpr int XS_ELEMS = 72 * PS;
    __shared__ __align__(16) __hip_bfloat16 smem[XS_ELEMS + CIN];  // xs + zero region
    __hip_bfloat16* xs = smem;

    const int tid  = threadIdx.x;
    const int wave = tid >> 6, lane = tid & 63;
    const int m16  = lane & 15, quad = lane >> 4;
    const int b0   = blockIdx.x * 2;   // local image index (2 images/block)

    if (tid < CIN) smem[XS_ELEMS + tid] = __float2bfloat16(0.f);  // SAME-pad zeros

    f32x4 acc[5][2];
#pragma unroll
    for (int i = 0; i < 5; ++i) { acc[i][0] = f32x4{0,0,0,0}; acc[i][1] = f32x4{0,0,0,0}; }

    const int bo0 = wave * 1024 + lane * 8;          // ct=0 frag (elems)
    const int bo1 = bo0 + 512;                       // ct=1 frag

    constexpr int CHPP = CIN / 8;
    auto stage = [&](int ap) {
        const __hip_bfloat16* inb = in + (size_t)ap * planeA + (size_t)b0 * 36 * CIN;
        __syncthreads();   // all waves done reading previous xs (covers zs init at ap=0)
        for (int c = tid; c < 72 * CHPP; c += 256) {
            int pix = c / CHPP;
            int off = (c - pix * CHPP) * 8;
            *(int4v*)(xs + pix * PS + off) = *(const int4v*)(inb + pix * CIN + off);
        }
        __syncthreads();
    };

    stage(0);
    conv_pass<CIN, 2>(smem, wt,              planeW, acc, m16, quad, bo0, bo1); // A0 x {W0,W1}
    conv_pass<CIN, 1>(smem, wt + 2 * planeW, planeW, acc, m16, quad, bo0, bo1); // A0 x {W2}
    stage(1);
    conv_pass<CIN, 2>(smem, wt,              planeW, acc, m16, quad, bo0, bo1); // A1 x {W0,W1}
    stage(2);
    conv_pass<CIN, 1>(smem, wt,              planeW, acc, m16, quad, bo0, bo1); // A2 x {W0}

    // epilogue: fused BN scale/bias + relu, split-store 3 bf16 planes
#pragma unroll
    for (int ct = 0; ct < 2; ++ct) {
        const int n = wave * 32 + ct * 16 + m16;
        const float sc = scale[n], bi = biasf[n];
#pragma unroll
        for (int rt = 0; rt < 5; ++rt) {
            const int mrow = rt * 16 + quad * 4;
            if (mrow < 72) {
#pragma unroll
                for (int r = 0; r < 4; ++r) {
                    float v = fmaxf(acc[rt][ct][r] * sc + bi, 0.f);
                    __hip_bfloat16 s0, s1, s2;
                    split3(v, s0, s1, s2);
                    size_t idx = (size_t)(b0 * 36 + mrow + r) * 128 + n;
                    out[idx] = s0; out[idx + planeO] = s1; out[idx + 2 * planeO] = s2;
                }
            }
        }
    }
}

// ---------------- FC1 partial GEMM: A-plane grouped, runtime K-split ----------------
// All NS partial slots are summed in heads_k, so a block accumulates several
// plane-pairs into ONE acc. g0 = A0 x {W0,W1,W2}, g1 = A1 x {W0,W1}, g2 = A2 x {W0}.
// NS=12 at both chunk sizes (even 9 blocks/CU at CH=4096). Prefetch clamps
// dropped (over-reads land in adjacent mapped ws arrays, values discarded).

template<int NW>
__device__ __forceinline__ void fc_body(
    const __hip_bfloat16* __restrict__ Ap,    // A-plane base (g applied)
    const __hip_bfloat16* __restrict__ Bp,    // Bw + nblk*4096 (W-plane 0)
    size_t planeBW, int kt0, int NKT,
    float* __restrict__ outp, size_t m0,
    __hip_bfloat16* smem, int tid, int wave, int lane)
{
    constexpr int ABUF = 4096;
    const int m16 = lane & 15, quad = lane >> 4;
    const int wr = wave >> 1, wc = wave & 1;
    const int cr = tid >> 2, co = (tid & 3) * 8;

    f32x4 acc[4][4];
#pragma unroll
    for (int i = 0; i < 4; ++i)
#pragma unroll
        for (int j = 0; j < 4; ++j) acc[i][j] = f32x4{0,0,0,0};

    int ao[4];
#pragma unroll
    for (int i = 0; i < 4; ++i) ao[i] = wr * 2048 + i * 512 + lane * 8;
    const int bofs = wc * 2048 + lane * 8;
    const int adst = ((cr >> 4) & 3) * 512 + (tid & 3) * 128 + (cr & 15) * 8;

    auto ldA = [&](int ktr, int4v& a0, int4v& a1) {   // ktr relative to kt0
        const __hip_bfloat16* base = Ap + (m0 + cr) * 4608 + (kt0 + ktr) * 32 + co;
        a0 = *(const int4v*)base;
        a1 = *(const int4v*)(base + (size_t)64 * 4608);
    };
    auto ldB = [&](int p, bf16x8* bf) {               // phase p -> (ktr, w)
        const int ktr = p / NW, w = p - ktr * NW;
        const __hip_bfloat16* base = Bp + (size_t)w * planeBW
                                   + (size_t)(kt0 + ktr) * 24576 + bofs;
#pragma unroll
        for (int i = 0; i < 4; ++i) bf[i] = *(const bf16x8*)(base + i * 512);
    };
    auto stA = [&](int buf, int4v a0, int4v a1) {
        __hip_bfloat16* base = smem + buf * ABUF;
        *(int4v*)(base + adst) = a0;                  // rows 0..63
        *(int4v*)(base + 2048 + adst) = a1;           // rows 64..127
    };

    // prologue
    int4v pa0, pa1, qa0, qa1;
    bf16x8 Bc[4], B1[4], Bn[4];
    {
        int4v a0, a1;
        ldA(0, a0, a1);
        ldB(0, Bc);
        ldA(1, pa0, pa1);
        ldB(1, B1);
        stA(0, a0, a1);
    }
    __syncthreads();
    int cur = 0;

#pragma unroll 2
    for (int ktr = 0; ktr < NKT; ++ktr) {
        // A prefetch, 2-kt slack; unconditional (tail over-read lands in the
        // next mapped ws array, discarded)
        ldA(ktr + 2, qa0, qa1);
        // A fragments for this kt, shared across all NW B-phases
        const __hip_bfloat16* base = smem + cur * ABUF;
        bf16x8 af[4];
#pragma unroll
        for (int i = 0; i < 4; ++i) af[i] = *(const bf16x8*)(base + ao[i]);
#pragma unroll
        for (int w = 0; w < NW; ++w) {
            ldB(ktr * NW + w + 2, Bn);                // unconditional (pad-read at tail)
#pragma unroll
            for (int i = 0; i < 4; ++i)
#pragma unroll
                for (int j = 0; j < 4; ++j)
                    acc[i][j] = mfma16(af[i], Bc[j], acc[i][j]);
#pragma unroll
            for (int i = 0; i < 4; ++i) { Bc[i] = B1[i]; B1[i] = Bn[i]; }
        }
        if (ktr + 1 < NKT) stA(cur ^ 1, pa0, pa1);    // waits loads issued last kt
        __syncthreads();
        cur ^= 1;
        pa0 = qa0; pa1 = qa1;
    }

#pragma unroll
    for (int i = 0; i < 4; ++i) {
        const int row = wr * 64 + i * 16 + quad * 4;
#pragma unroll
        for (int j = 0; j < 4; ++j) {
            const int col = wc * 64 + j * 16 + m16;
#pragma unroll
            for (int r = 0; r < 4; ++r)
                outp[(m0 + row + r) * 768 + col] = acc[i][j][r];
        }
    }
}

__global__ __launch_bounds__(256, 3)
void fc_partial_k(const __hip_bfloat16* __restrict__ A, size_t planeF,    // 3 planes (CH,4608)
                  const __hip_bfloat16* __restrict__ Bw, size_t planeBW,  // 3 planes frag-major [144][24576]
                  float* __restrict__ partial,                            // [NS](CH,768)
                  int chunk, int ns6)
{
    constexpr int ABUF = 4096;
    __shared__ __align__(16) __hip_bfloat16 smem[2 * ABUF];   // 16 KB
    const int tid = threadIdx.x, wave = tid >> 6, lane = tid & 63;
    const int nmblk = chunk >> 7;
    const int mblk = blockIdx.x & (nmblk - 1);
    int rest = blockIdx.x / nmblk;
    const int nblk = rest % 6;
    const int slot = rest / 6;
    const size_t m0 = (size_t)mblk * 128;

    const __hip_bfloat16* Bp = Bw + (size_t)nblk * 4096;
    float* outp = partial + (size_t)slot * chunk * 768 + (size_t)nblk * 128;

    if (ns6) {   // NS=6: g0 slots 0-2 (NKT 48), g1 slots 3-4 (72), g2 slot 5 (144)
        if (slot < 3)
            fc_body<3>(A, Bp, planeBW, slot * 48, 48, outp, m0, smem, tid, wave, lane);
        else if (slot < 5)
            fc_body<2>(A + planeF, Bp, planeBW, (slot - 3) * 72, 72, outp, m0, smem, tid, wave, lane);
        else
            fc_body<1>(A + 2 * planeF, Bp, planeBW, 0, 144, outp, m0, smem, tid, wave, lane);
    } else {     // NS=12: g0 slots 0-5 (24), g1 slots 6-9 (36), g2 slots 10-11 (72)
        if (slot < 6)
            fc_body<3>(A, Bp, planeBW, slot * 24, 24, outp, m0, smem, tid, wave, lane);
        else if (slot < 10)
            fc_body<2>(A + planeF, Bp, planeBW, (slot - 6) * 36, 36, outp, m0, smem, tid, wave, lane);
        else
            fc_body<1>(A + 2 * planeF, Bp, planeBW, (slot - 10) * 72, 72, outp, m0, smem, tid, wave, lane);
    }
}

// ---------------- heads: partial-sum + LN + small GEMVs + argmax + dueling (fp32) ----------------

__global__ __launch_bounds__(256)
void heads_k(const float* __restrict__ partial,          // [ns](CH,768): [piece|value|move]
             const float* __restrict__ biasfc,           // 768
             const float* __restrict__ pln_g, const float* __restrict__ pln_b,
             const float* __restrict__ pfc2_w, const float* __restrict__ pfc2_b,
             const float* __restrict__ mln_g, const float* __restrict__ mln_b,
             const float* __restrict__ mfc2_w, const float* __restrict__ mfc2_b,
             const float* __restrict__ vln_g, const float* __restrict__ vln_b,
             const float* __restrict__ vfc2_w, const float* __restrict__ vfc2_b,
             const float* __restrict__ selw,             // (36,256)
             float* __restrict__ q,                      // (B,1296) full
             int b_base, int ns, int chunk)
{
    __shared__ float hp[256], hv[256], hm[256];
    __shared__ float pl[36], ml[36];
    __shared__ float red[4];
    __shared__ float valv, plm_s, mlm_s;
    __shared__ int amax_s;

    const int tid = threadIdx.x, wave = tid >> 6, lane = tid & 63;
    const size_t b = blockIdx.x;                // local
    const size_t bg = b_base + b;               // global

    // inline fc-reduce: sum ns partials + bias
    float pp = biasfc[tid], vv = biasfc[256 + tid], mm = biasfc[512 + tid];
    for (int k = 0; k < ns; ++k) {
        const float* row = partial + (size_t)k * chunk * 768 + b * 768;
        pp += row[tid]; vv += row[256 + tid]; mm += row[512 + tid];
    }

    auto warpSum = [&](float v) {
        v += __shfl_xor(v, 1);  v += __shfl_xor(v, 2);  v += __shfl_xor(v, 4);
        v += __shfl_xor(v, 8);  v += __shfl_xor(v, 16); v += __shfl_xor(v, 32);
        return v;
    };
    auto blockSum = [&](float v) {
        v = warpSum(v);
        if (lane == 0) red[wave] = v;
        __syncthreads();
        float s = red[0] + red[1] + red[2] + red[3];
        __syncthreads();
        return s;
    };
    auto lnrelu = [&](float x, const float* g, const float* bb) {
        float mu  = blockSum(x) * (1.f / 256.f);
        float d   = x - mu;
        float var = blockSum(d * d) * (1.f / 256.f);
        float y   = d * rsqrtf(var + 1e-5f) * g[tid] + bb[tid];
        return fmaxf(y, 0.f);
    };

    hp[tid] = lnrelu(pp, pln_g, pln_b);
    hv[tid] = lnrelu(vv, vln_g, vln_b);
    __syncthreads();

    {
        float h0 = hp[lane], h1 = hp[64 + lane], h2 = hp[128 + lane], h3 = hp[192 + lane];
#pragma unroll
        for (int jj = 0; jj < 9; ++jj) {
            int j = wave * 9 + jj;
            const float* wr_ = pfc2_w + j * 256;
            float s = h0 * wr_[lane] + h1 * wr_[64 + lane]
                    + h2 * wr_[128 + lane] + h3 * wr_[192 + lane];
            s = warpSum(s);
            if (lane == 0) pl[j] = s + pfc2_b[j];
        }
        if (wave == 0) {
            float g0 = hv[lane], g1 = hv[64 + lane], g2 = hv[128 + lane], g3 = hv[192 + lane];
            float s = g0 * vfc2_w[lane] + g1 * vfc2_w[64 + lane]
                    + g2 * vfc2_w[128 + lane] + g3 * vfc2_w[192 + lane];
            s = warpSum(s);
            if (lane == 0) valv = s + vfc2_b[0];
        }
    }
    __syncthreads();
    if (tid == 0) {   // first-max argmax (jnp semantics) + mean
        float m = -1e30f, s = 0.f; int idx = 0;
        for (int j = 0; j < 36; ++j) { float v = pl[j]; s += v; if (v > m) { m = v; idx = j; } }
        plm_s = s * (1.f / 36.f); amax_s = idx;
    }
    __syncthreads();

    mm += selw[amax_s * 256 + tid];   // one-hot concat == single column add
    hm[tid] = lnrelu(mm, mln_g, mln_b);
    __syncthreads();
    {
        float h0 = hm[lane], h1 = hm[64 + lane], h2 = hm[128 + lane], h3 = hm[192 + lane];
#pragma unroll
        for (int jj = 0; jj < 9; ++jj) {
            int j = wave * 9 + jj;
            const float* wr_ = mfc2_w + j * 256;
            float s = h0 * wr_[lane] + h1 * wr_[64 + lane]
                    + h2 * wr_[128 + lane] + h3 * wr_[192 + lane];
            s = warpSum(s);
            if (lane == 0) ml[j] = s + mfc2_b[j];
        }
    }
    __syncthreads();
    if (tid == 0) {
        float s = 0.f;
        for (int j = 0; j < 36; ++j) s += ml[j];
        mlm_s = s * (1.f / 36.f);
    }
    __syncthreads();

    const float val = valv, plm = plm_s, mlm = mlm_s;
    for (int idx = tid; idx < 1296; idx += 256) {
        int i = idx / 36, j = idx - i * 36;
        q[bg * 1296 + idx] = val + (pl[i] - plm) + (ml[j] - mlm);
    }
}

// ---------------- launch ----------------

extern "C" void kernel_launch(void* const* d_in, const int* in_sizes, int n_in,
                              void* d_out, int out_size, void* d_ws, size_t ws_size,
                              hipStream_t stream)
{
    const float* x       = (const float*)d_in[0];
    const float* conv1_w = (const float*)d_in[1];
    const float* conv1_b = (const float*)d_in[2];
    const float* bn1_g   = (const float*)d_in[3];
    const float* bn1_b   = (const float*)d_in[4];
    const float* bn1_m   = (const float*)d_in[5];
    const float* bn1_v   = (const float*)d_in[6];
    const float* conv2_w = (const float*)d_in[7];
    const float* conv2_b = (const float*)d_in[8];
    const float* bn2_g   = (const float*)d_in[9];
    const float* bn2_b   = (const float*)d_in[10];
    const float* bn2_m   = (const float*)d_in[11];
    const float* bn2_v   = (const float*)d_in[12];
    const float* conv3_w = (const float*)d_in[13];
    const float* conv3_b = (const float*)d_in[14];
    const float* bn3_g   = (const float*)d_in[15];
    const float* bn3_b   = (const float*)d_in[16];
    const float* bn3_m   = (const float*)d_in[17];
    const float* bn3_v   = (const float*)d_in[18];
    const float* pfc1_w  = (const float*)d_in[19];
    const float* pfc1_b  = (const float*)d_in[20];
    const float* pln_g   = (const float*)d_in[21];
    const float* pln_b   = (const float*)d_in[22];
    const float* pfc2_w  = (const float*)d_in[23];
    const float* pfc2_b  = (const float*)d_in[24];
    const float* mfc1_w  = (const float*)d_in[25];
    const float* mfc1_b  = (const float*)d_in[26];
    const float* mln_g   = (const float*)d_in[27];
    const float* mln_b   = (const float*)d_in[28];
    const float* mfc2_w  = (const float*)d_in[29];
    const float* mfc2_b  = (const float*)d_in[30];
    const float* vfc1_w  = (const float*)d_in[31];
    const float* vfc1_b  = (const float*)d_in[32];
    const float* vln_g   = (const float*)d_in[33];
    const float* vln_b   = (const float*)d_in[34];
    const float* vfc2_w  = (const float*)d_in[35];
    const float* vfc2_b  = (const float*)d_in[36];

    const size_t planeW2 = 576 * 128;               // conv2 weight plane elems
    const size_t planeW3 = 1152 * 128;              // conv3 weight plane elems
    const size_t planeBW = (size_t)4608 * 768;      // fc weight plane elems
    const size_t WPAD    = 4096 * 2;                // one kt-slice pad (bytes), kept for layout stability

    // workspace layout size for a given (chunk, n_slots)
    auto layout_total = [&](int CHv, int NSv) -> size_t {
        size_t t = 0;
        auto add = [&](size_t b) { t += (b + 255) & ~(size_t)255; };
        add(3 * planeW2 * 2 + WPAD); add(3 * planeW3 * 2 + WPAD); add(3 * planeBW * 2);
        add(36 * 256 * 4);
        add(64 * 4); add(64 * 4); add(128 * 4); add(128 * 4);
        add(128 * 4); add(128 * 4); add(768 * 4);
        size_t pA2 = (size_t)CHv * 36 * 128;
        add(3 * pA2 * 2);                                      // A1
        size_t par = (size_t)NSv * CHv * 768 * 4;
        add((3 * pA2 * 2 > par) ? 3 * pA2 * 2 : par);          // A2
        return t;
    };

    // 3-tier runtime config: prefer CH=4096 + NS=12 (~287 MB), else CH=4096 +
    // NS=6 (~249 MB, proven in R6/R8), else the proven CH=2048/12 config.
    int CH, NS;
    if (layout_total(4096, 12) <= ws_size)     { CH = 4096; NS = 12; }
    else if (layout_total(4096, 6) <= ws_size) { CH = 4096; NS = 6;  }
    else                                       { CH = 2048; NS = 12; }
    const int ns6 = (NS == 6);
    const int NCH = BQ / CH;

    const size_t planeA1 = (size_t)CH * 36 * 64;
    const size_t planeA2 = (size_t)CH * 36 * 128;

    char* ws = (char*)d_ws;
    size_t off = 0;
    auto alloc = [&](size_t bytes) -> char* {
        char* p = ws + off; off += (bytes + 255) & ~(size_t)255; return p;
    };
    __hip_bfloat16* w2t  = (__hip_bfloat16*)alloc(3 * planeW2 * 2 + WPAD);
    __hip_bfloat16* w3t  = (__hip_bfloat16*)alloc(3 * planeW3 * 2 + WPAD);
    __hip_bfloat16* bigw = (__hip_bfloat16*)alloc(3 * planeBW * 2);
    float* selw   = (float*)alloc(36 * 256 * 4);
    float* scale1 = (float*)alloc(64 * 4);
    float* bias1f = (float*)alloc(64 * 4);
    float* scale2 = (float*)alloc(128 * 4);
    float* bias2f = (float*)alloc(128 * 4);
    float* scale3 = (float*)alloc(128 * 4);
    float* bias3f = (float*)alloc(128 * 4);
    float* biasfc = (float*)alloc(768 * 4);
    // ping-pong arenas, per-chunk: A1: h1 -> h3 ; A2: h2 -> fc partials
    size_t parBytes = (size_t)NS * CH * 768 * 4;
    char* A1 = alloc(3 * planeA2 * 2);
    char* A2 = alloc((3 * planeA2 * 2 > parBytes) ? 3 * planeA2 * 2 : parBytes);

    prep_scalars_k<<<1, 768, 0, stream>>>(
        conv1_b, bn1_g, bn1_b, bn1_m, bn1_v,
        conv2_b, bn2_g, bn2_b, bn2_m, bn2_v,
        conv3_b, bn3_g, bn3_b, bn3_m, bn3_v,
        pfc1_b, vfc1_b, mfc1_b,
        scale1, bias1f, scale2, bias2f, scale3, bias3f, biasfc);
    prep_convw_k<64><<<288, 256, 0, stream>>>(conv2_w, w2t, planeW2);
    prep_convw_k<128><<<576, 256, 0, stream>>>(conv3_w, w3t, planeW3);
    prep_bigw_k<<<13824, 256, 0, stream>>>(pfc1_w, vfc1_w, mfc1_w, bigw, planeBW);
    prep_selw_k<<<36, 256, 0, stream>>>(mfc1_w, selw);

    __hip_bfloat16* h1s  = (__hip_bfloat16*)A1;
    __hip_bfloat16* h2s  = (__hip_bfloat16*)A2;
    __hip_bfloat16* h3s  = (__hip_bfloat16*)A1;   // overwrites h1s (dead after conv2)
    float*          fpar = (float*)A2;            // overwrites h2s (dead after conv3)

    for (int cchunk = 0; cchunk < NCH; ++cchunk) {
        const int b_base = cchunk * CH;
        conv1_k<<<CH * 9, 256, 0, stream>>>(
            x, conv1_w, scale1, bias1f, h1s, planeA1, b_base);
        conv_gemm_k<64><<<CH / 2, 256, 0, stream>>>(
            h1s, planeA1, w2t, planeW2, scale2, bias2f, h2s, planeA2);
        conv_gemm_k<128><<<CH / 2, 256, 0, stream>>>(
            h2s, planeA2, w3t, planeW3, scale3, bias3f, h3s, planeA2);
        fc_partial_k<<<(CH / 128) * 6 * NS, 256, 0, stream>>>(
            h3s, planeA2, bigw, planeBW, fpar, CH, ns6);
        heads_k<<<CH, 256, 0, stream>>>(fpar, biasfc,
            pln_g, pln_b, pfc2_w, pfc2_b,
            mln_g, mln_b, mfc2_w, mfc2_b,
            vln_g, vln_b, vfc2_w, vfc2_b,
            selw, (float*)d_out, b_base, NS, CH);
    }
}